// Round 13
// baseline (268.367 us; speedup 1.0000x reference)
//
#include <hip/hip_runtime.h>
#include <math.h>

// Problem constants (GumbelVectorQuantizer): B=16,T=2048,D=512,M=1024
#define NTOT 32768   // B*T
#define DDIM 512
#define MDIM 1024
#define QOFF 16777216  // quantized element count (output scalars follow)
#define NREP 128       // atomic-spread replicas (wave-indexed)

typedef _Float16 f16x8 __attribute__((ext_vector_type(8)));
typedef float    f32x4 __attribute__((ext_vector_type(4)));

// async global->LDS: per-LANE global src pointer, wave-uniform LDS dest base
__device__ __forceinline__ void gload_lds16(const void* g, void* l) {
  __builtin_amdgcn_global_load_lds(
      (const __attribute__((address_space(1))) void*)g,
      (__attribute__((address_space(3))) void*)l, 16, 0, 0);
}

// ---------------------------------------------------------------------------
// esq[m] = sum_d e[m][d]^2
__global__ __launch_bounds__(256) void esq_kernel(const float* __restrict__ e,
                                                  float* __restrict__ esq) {
  const int w = threadIdx.x >> 6, lane = threadIdx.x & 63;
  const int m = blockIdx.x * 4 + w;
  const float4* row = (const float4*)(e + (size_t)m * DDIM);
  const float4 a = row[lane * 2];
  const float4 b = row[lane * 2 + 1];
  float s = ((a.x * a.x + a.y * a.y) + (a.z * a.z + a.w * a.w)) +
            ((b.x * b.x + b.y * b.y) + (b.z * b.z + b.w * b.w));
#pragma unroll
  for (int off = 32; off; off >>= 1) s += __shfl_xor(s, off);
  if (lane == 0) esq[m] = s;
}

// ---------------------------------------------------------------------------
// xsq partial sums -> NREP cache-line-strided slots (atomic-spread)
__global__ __launch_bounds__(256)
void xsq_kernel(const float* __restrict__ x, float* __restrict__ xsq_rep) {
  const int tid = blockIdx.x * 256 + threadIdx.x;   // 262144 threads
  const float4* xv = (const float4*)x;
  float s = 0.f;
#pragma unroll
  for (int i = 0; i < 16; ++i) {
    const float4 a = xv[(size_t)i * 262144 + tid];
    s += (a.x * a.x + a.y * a.y) + (a.z * a.z + a.w * a.w);
  }
#pragma unroll
  for (int off = 32; off; off >>= 1) s += __shfl_xor(s, off);
  if ((threadIdx.x & 63) == 0)
    atomicAdd(&xsq_rep[(blockIdx.x & (NREP - 1)) * 16], s);
}

// ---------------------------------------------------------------------------
// Pre-swizzle E into MFMA B-fragment order, fp16 hi/lo split.
// Flat order: [mt(8)][ks(16)][ctg(8)][lane(64)][8 halves].
__global__ __launch_bounds__(256) void e_to_frag(const float* __restrict__ e,
                                                 _Float16* __restrict__ hi,
                                                 _Float16* __restrict__ lo) {
  const int tid = blockIdx.x * 256 + threadIdx.x;   // 65536 threads
  const int lane = tid & 63;
  const int F = tid >> 6;            // F = mt*128 + ks*8 + ctg
  const int mt = F >> 7;
  const int ks = (F >> 3) & 15;
  const int ctg = F & 7;
  const int m = mt * 128 + ctg * 16 + (lane & 15);
  const int k0 = ks * 32 + (lane >> 4) * 8;
  const float* src = e + (size_t)m * DDIM + k0;
  const float4 a = *(const float4*)src;
  const float4 b = *(const float4*)(src + 4);
  f16x8 vh, vl;
  vh[0] = (_Float16)a.x; vl[0] = (_Float16)(a.x - (float)vh[0]);
  vh[1] = (_Float16)a.y; vl[1] = (_Float16)(a.y - (float)vh[1]);
  vh[2] = (_Float16)a.z; vl[2] = (_Float16)(a.z - (float)vh[2]);
  vh[3] = (_Float16)a.w; vl[3] = (_Float16)(a.w - (float)vh[3]);
  vh[4] = (_Float16)b.x; vl[4] = (_Float16)(b.x - (float)vh[4]);
  vh[5] = (_Float16)b.y; vl[5] = (_Float16)(b.y - (float)vh[5]);
  vh[6] = (_Float16)b.z; vl[6] = (_Float16)(b.z - (float)vh[6]);
  vh[7] = (_Float16)b.w; vl[7] = (_Float16)(b.w - (float)vh[7]);
  *(f16x8*)(hi + (size_t)tid * 8) = vh;
  *(f16x8*)(lo + (size_t)tid * 8) = vl;
}

// ---------------------------------------------------------------------------
// GEMM: dmap' = 10 * X.E^T - 5*||e||^2 (m97 structure + XCD remap; at its
// structure ceiling ~963 TF-equivalent -- UNCHANGED).
#define CVT1(RT, J, V)                                                         \
  Ah[RT][J] = (_Float16)(V);                                                   \
  Al[RT][J] = (_Float16)((V) - (float)Ah[RT][J]);
#define CVT8(RT, A0, A1)                                                       \
  CVT1(RT, 0, A0[0]) CVT1(RT, 1, A0[1]) CVT1(RT, 2, A0[2]) CVT1(RT, 3, A0[3]) \
  CVT1(RT, 4, A1[0]) CVT1(RT, 5, A1[1]) CVT1(RT, 6, A1[2]) CVT1(RT, 7, A1[3])

#define STAGE(AsP, BhP, BlP, KS)                                               \
  {                                                                            \
    _Pragma("unroll") for (int i_ = 0; i_ < 4; ++i_) {                         \
      const int row_ = (w * 4 + i_) * 8 + (lane >> 3);                         \
      const int cf_ = ((lane & 7) ^ (row_ & 7)) * 4;                           \
      gload_lds16(x + (size_t)(n0 + row_) * DDIM + (KS) * 32 + cf_,            \
                  (AsP) + (w * 4 + i_) * 1024);                                \
    }                                                                          \
    _Pragma("unroll") for (int i_ = 0; i_ < 2; ++i_) {                         \
      const size_t so_ =                                                       \
          (size_t)(mt * 16 + (KS)) * 8192 + (w * 2 + i_) * 1024 + lane * 16;   \
      gload_lds16((const char*)ehi + so_, (BhP) + (w * 2 + i_) * 1024);        \
      gload_lds16((const char*)elo + so_, (BlP) + (w * 2 + i_) * 1024);        \
    }                                                                          \
  }

#define COMPUTE(AsP, BhP, BlP)                                                 \
  {                                                                            \
    f16x8 Bhf[8], Blf[8];                                                      \
    _Pragma("unroll") for (int c_ = 0; c_ < 8; ++c_) {                         \
      Bhf[c_] = *(const f16x8*)((BhP) + c_ * 1024 + lane * 16);                \
      Blf[c_] = *(const f16x8*)((BlP) + c_ * 1024 + lane * 16);                \
    }                                                                          \
    f16x8 Ah[2], Al[2];                                                        \
    _Pragma("unroll") for (int rt_ = 0; rt_ < 2; ++rt_) {                      \
      const int row_ = w * 32 + rt_ * 16 + l15;                                \
      const int sw_ = (row_ & 7) << 4;                                         \
      const char* rb_ = (AsP) + row_ * 128;                                    \
      const f32x4 a0_ = *(const f32x4*)(rb_ + ((lg * 32) ^ sw_));              \
      const f32x4 a1_ = *(const f32x4*)(rb_ + ((lg * 32 + 16) ^ sw_));         \
      CVT8(rt_, a0_, a1_)                                                      \
    }                                                                          \
    _Pragma("unroll") for (int c_ = 0; c_ < 8; ++c_)                           \
        _Pragma("unroll") for (int rt_ = 0; rt_ < 2; ++rt_)                    \
            acc[rt_][c_] = __builtin_amdgcn_mfma_f32_16x16x32_f16(             \
                Ah[rt_], Bhf[c_], acc[rt_][c_], 0, 0, 0);                      \
    _Pragma("unroll") for (int c_ = 0; c_ < 8; ++c_)                           \
        _Pragma("unroll") for (int rt_ = 0; rt_ < 2; ++rt_)                    \
            acc[rt_][c_] = __builtin_amdgcn_mfma_f32_16x16x32_f16(             \
                Al[rt_], Bhf[c_], acc[rt_][c_], 0, 0, 0);                      \
    _Pragma("unroll") for (int c_ = 0; c_ < 8; ++c_)                           \
        _Pragma("unroll") for (int rt_ = 0; rt_ < 2; ++rt_)                    \
            acc[rt_][c_] = __builtin_amdgcn_mfma_f32_16x16x32_f16(             \
                Ah[rt_], Blf[c_], acc[rt_][c_], 0, 0, 0);                      \
  }

__global__ __launch_bounds__(256, 2)
void gemm_dmap(const float* __restrict__ x, const _Float16* __restrict__ ehi,
               const _Float16* __restrict__ elo, const float* __restrict__ esq,
               float* __restrict__ dmap) {
  __shared__ __align__(16) char smem[66048];
  char* const AsA = smem;              // A slab fp32 [128][32] = 16 KB
  char* const AsB = smem + 16384;
  char* const BhA = smem + 32768;      // B hi frag slab 8 KB
  char* const BhB = smem + 40960;
  char* const BlA = smem + 49152;      // B lo frag slab 8 KB
  char* const BlB = smem + 57344;
  float* const esqt = (float*)(smem + 65536);

  const int t = threadIdx.x;
  const int w = t >> 6;
  const int lane = t & 63;
  const int l15 = lane & 15;
  const int lg = lane >> 4;

  // XCD-aware remap (bijective only when rowblocks%8==0; else identity)
  int mt, nt;
  const int rowblocks = gridDim.x >> 3;
  if ((rowblocks & 7) == 0) {
    const int r = blockIdx.x & 7;        // ~XCD id (dispatch round-robin)
    const int q = blockIdx.x >> 3;
    mt = q & 7;
    nt = r + 8 * (q >> 3);
  } else {
    mt = blockIdx.x & 7;
    nt = blockIdx.x >> 3;
  }
  const int n0 = nt * 128;

  if (t < 128) esqt[t] = esq[mt * 128 + t];

  f32x4 acc[2][8];
#pragma unroll
  for (int rt = 0; rt < 2; ++rt)
#pragma unroll
    for (int c = 0; c < 8; ++c) acc[rt][c] = (f32x4){0.f, 0.f, 0.f, 0.f};

  STAGE(AsA, BhA, BlA, 0)
  __syncthreads();

  for (int kk = 0; kk < 8; ++kk) {
    const int ks = kk * 2;
    STAGE(AsB, BhB, BlB, ks + 1)
    COMPUTE(AsA, BhA, BlA)
    __syncthreads();
    if (ks + 2 < 16) STAGE(AsA, BhA, BlA, ks + 2)
    COMPUTE(AsB, BhB, BlB)
    __syncthreads();
  }

#pragma unroll
  for (int rt = 0; rt < 2; ++rt)
#pragma unroll
    for (int ct = 0; ct < 8; ++ct) {
      const float e5 = 5.f * esqt[ct * 16 + l15];
      float* dr = dmap + (size_t)(n0 + w * 32 + rt * 16 + lg * 4) * 1024 +
                  mt * 128 + ct * 16 + l15;
#pragma unroll
      for (int rg = 0; rg < 4; ++rg)
        dr[(size_t)rg * 1024] = 10.f * acc[rt][ct][rg] - e5;
    }
}

// ---------------------------------------------------------------------------
#define AMAX(V, MM)                                                            \
  { const float v_ = (V); const int m_ = (MM);                                 \
    if (v_ > bv || (v_ == bv && m_ < bi)) { bv = v_; bi = m_; } }
#define GMAXD(V, MM, DV)                                                       \
  { const float v_ = (V); const int m_ = (MM);                                 \
    if (v_ > gv || (v_ == gv && m_ < gi)) { gv = v_; gi = m_; dv = (DV); } }

// per-row work: argmax->counts_rep, softmax->cav, gumbel argmax->(gi,dv),
// gather emb[gi]->out, sd_wave += dmap'[n][gi]  (SSE identity, no x read)
#define ROWBODY(N)                                                             \
  {                                                                            \
    const int n_ = (N);                                                        \
    const float* Dr = dmap + (size_t)n_ * MDIM;                                \
    const float4* grow = (const float4*)(gum + (size_t)n_ * MDIM);             \
    const float4 q0 = grow[lane];                                              \
    const float4 q1 = grow[lane + 64];                                         \
    const float4 q2 = grow[lane + 128];                                        \
    const float4 q3 = grow[lane + 192];                                        \
    const float4 d0 = *(const float4*)&Dr[co];                                 \
    const float4 d1 = *(const float4*)&Dr[co + 256];                           \
    const float4 d2 = *(const float4*)&Dr[co + 512];                           \
    const float4 d3 = *(const float4*)&Dr[co + 768];                           \
    float bv = -3.402823466e+38f; int bi = 0;                                  \
    AMAX(d0.x, co + 0)   AMAX(d0.y, co + 1)   AMAX(d0.z, co + 2)   AMAX(d0.w, co + 3)   \
    AMAX(d1.x, co + 256) AMAX(d1.y, co + 257) AMAX(d1.z, co + 258) AMAX(d1.w, co + 259) \
    AMAX(d2.x, co + 512) AMAX(d2.y, co + 513) AMAX(d2.z, co + 514) AMAX(d2.w, co + 515) \
    AMAX(d3.x, co + 768) AMAX(d3.y, co + 769) AMAX(d3.z, co + 770) AMAX(d3.w, co + 771) \
    _Pragma("unroll") for (int off = 32; off; off >>= 1) {                     \
      const float ov = __shfl_xor(bv, off);                                    \
      const int oi = __shfl_xor(bi, off);                                      \
      if (ov > bv || (ov == bv && oi < bi)) { bv = ov; bi = oi; }              \
    }                                                                          \
    if (lane == 0) atomicAdd(&counts_rep[repM + bi], 1);                       \
    float4 p0, p1, p2, p3;                                                     \
    p0.x = __expf(d0.x - bv); p0.y = __expf(d0.y - bv);                        \
    p0.z = __expf(d0.z - bv); p0.w = __expf(d0.w - bv);                        \
    p1.x = __expf(d1.x - bv); p1.y = __expf(d1.y - bv);                        \
    p1.z = __expf(d1.z - bv); p1.w = __expf(d1.w - bv);                        \
    p2.x = __expf(d2.x - bv); p2.y = __expf(d2.y - bv);                        \
    p2.z = __expf(d2.z - bv); p2.w = __expf(d2.w - bv);                        \
    p3.x = __expf(d3.x - bv); p3.y = __expf(d3.y - bv);                        \
    p3.z = __expf(d3.z - bv); p3.w = __expf(d3.w - bv);                        \
    float ssum = (((p0.x + p0.y) + (p0.z + p0.w)) + ((p1.x + p1.y) + (p1.z + p1.w))) + \
                 (((p2.x + p2.y) + (p2.z + p2.w)) + ((p3.x + p3.y) + (p3.z + p3.w)));  \
    _Pragma("unroll") for (int off = 32; off; off >>= 1)                       \
        ssum += __shfl_xor(ssum, off);                                         \
    const float inv = 1.0f / ssum;                                             \
    cav0.x += p0.x * inv; cav0.y += p0.y * inv;                                \
    cav0.z += p0.z * inv; cav0.w += p0.w * inv;                                \
    cav1.x += p1.x * inv; cav1.y += p1.y * inv;                                \
    cav1.z += p1.z * inv; cav1.w += p1.w * inv;                                \
    cav2.x += p2.x * inv; cav2.y += p2.y * inv;                                \
    cav2.z += p2.z * inv; cav2.w += p2.w * inv;                                \
    cav3.x += p3.x * inv; cav3.y += p3.y * inv;                                \
    cav3.z += p3.z * inv; cav3.w += p3.w * inv;                                \
    float gv = -3.402823466e+38f, dv = 0.f; int gi = 0;                        \
    GMAXD(d0.x + q0.x, co + 0, d0.x)     GMAXD(d0.y + q0.y, co + 1, d0.y)      \
    GMAXD(d0.z + q0.z, co + 2, d0.z)     GMAXD(d0.w + q0.w, co + 3, d0.w)      \
    GMAXD(d1.x + q1.x, co + 256, d1.x)   GMAXD(d1.y + q1.y, co + 257, d1.y)    \
    GMAXD(d1.z + q1.z, co + 258, d1.z)   GMAXD(d1.w + q1.w, co + 259, d1.w)    \
    GMAXD(d2.x + q2.x, co + 512, d2.x)   GMAXD(d2.y + q2.y, co + 513, d2.y)    \
    GMAXD(d2.z + q2.z, co + 514, d2.z)   GMAXD(d2.w + q2.w, co + 515, d2.w)    \
    GMAXD(d3.x + q3.x, co + 768, d3.x)   GMAXD(d3.y + q3.y, co + 769, d3.y)    \
    GMAXD(d3.z + q3.z, co + 770, d3.z)   GMAXD(d3.w + q3.w, co + 771, d3.w)    \
    _Pragma("unroll") for (int off = 32; off; off >>= 1) {                     \
      const float ov = __shfl_xor(gv, off);                                    \
      const int oi = __shfl_xor(gi, off);                                      \
      const float od = __shfl_xor(dv, off);                                    \
      if (ov > gv || (ov == gv && oi < gi)) { gv = ov; gi = oi; dv = od; }     \
    }                                                                          \
    sd_wave += dv;                                                             \
    const float4* erow = (const float4*)(emb + (size_t)gi * DDIM);             \
    float4* orow = (float4*)(out + (size_t)n_ * DDIM);                         \
    orow[lane] = erow[lane];                                                   \
    orow[lane + 64] = erow[lane + 64];                                         \
  }

// Streaming epilogue: r10 shape (1024 blocks x 4 waves x 8 rows/wave, natural
// regalloc) + no-x algebra + DIRECT wave-replica flush (r12 lesson: LDS
// atomic flush was the marginal cost; each wave covers all 1024 cols exactly
// once, so no intra-block combining needed -- no LDS, no barriers).
__global__ __launch_bounds__(256)
void epi(const float* __restrict__ emb, const float* __restrict__ dmap,
         const float* __restrict__ gum, float* __restrict__ out,
         float* __restrict__ avg_rep, int* __restrict__ counts_rep,
         float* __restrict__ sd_rep) {
  const int t = threadIdx.x;
  const int w = t >> 6;
  const int lane = t & 63;
  const int co = lane << 2;
  const int wrep = ((blockIdx.x << 2) + w) & (NREP - 1);  // wave's replica
  const int repM = wrep * MDIM;

  float4 cav0 = make_float4(0.f, 0.f, 0.f, 0.f);
  float4 cav1 = make_float4(0.f, 0.f, 0.f, 0.f);
  float4 cav2 = make_float4(0.f, 0.f, 0.f, 0.f);
  float4 cav3 = make_float4(0.f, 0.f, 0.f, 0.f);
  float sd_wave = 0.f;

  const int nb = blockIdx.x * 32 + w * 8;  // chunk-local row base (8 rows)
  for (int i = 0; i < 8; ++i) {
    ROWBODY(nb + i)
  }

  if (lane == 0) atomicAdd(&sd_rep[wrep * 16], sd_wave);

  // direct per-wave flush: 16 disjoint columns per lane -> 16 global atomics
  atomicAdd(&avg_rep[repM + co + 0], cav0.x);
  atomicAdd(&avg_rep[repM + co + 1], cav0.y);
  atomicAdd(&avg_rep[repM + co + 2], cav0.z);
  atomicAdd(&avg_rep[repM + co + 3], cav0.w);
  atomicAdd(&avg_rep[repM + co + 256], cav1.x);
  atomicAdd(&avg_rep[repM + co + 257], cav1.y);
  atomicAdd(&avg_rep[repM + co + 258], cav1.z);
  atomicAdd(&avg_rep[repM + co + 259], cav1.w);
  atomicAdd(&avg_rep[repM + co + 512], cav2.x);
  atomicAdd(&avg_rep[repM + co + 513], cav2.y);
  atomicAdd(&avg_rep[repM + co + 514], cav2.z);
  atomicAdd(&avg_rep[repM + co + 515], cav2.w);
  atomicAdd(&avg_rep[repM + co + 768], cav3.x);
  atomicAdd(&avg_rep[repM + co + 769], cav3.y);
  atomicAdd(&avg_rep[repM + co + 770], cav3.z);
  atomicAdd(&avg_rep[repM + co + 771], cav3.w);
}

// ---------------------------------------------------------------------------
__global__ __launch_bounds__(1024)
void finalize(const float* __restrict__ avg_rep, const int* __restrict__ counts_rep,
              const float* __restrict__ sd_rep, const float* __restrict__ xsq_rep,
              float* __restrict__ out) {
  __shared__ float red[32];
  const int t = threadIdx.x;
  float q = 0.f; int c = 0;
#pragma unroll
  for (int r = 0; r < NREP; ++r) {
    q += avg_rep[r * MDIM + t];
    c += counts_rep[r * MDIM + t];
  }
  const float invN = 1.f / 32768.f;
  const float p = (float)c * invN;
  float a = p * log2f(p + 1e-10f);
  const float qq = q * invN;
  float b = qq * log2f(qq + 1e-10f);
#pragma unroll
  for (int off = 32; off; off >>= 1) {
    a += __shfl_xor(a, off);
    b += __shfl_xor(b, off);
  }
  const int wv = t >> 6, ln = t & 63;
  if (ln == 0) { red[wv] = a; red[wv + 16] = b; }
  __syncthreads();
  if (t == 0) {
    float sa = 0.f, sb = 0.f;
#pragma unroll
    for (int i = 0; i < 16; ++i) { sa += red[i]; sb += red[i + 16]; }
    float sd = 0.f, xs = 0.f;
#pragma unroll
    for (int r = 0; r < NREP; ++r) { sd += sd_rep[r * 16]; xs += xsq_rep[r * 16]; }
    out[QOFF + 0] = -sa;                                // code_perplexity
    out[QOFF + 1] = -sb;                                // prob_perplexity
    const float sse = xs - sd * 0.2f;                   // SSE identity
    out[QOFF + 2] = sse * (1.f / (32768.f * 512.f));    // commitment_loss
  }
}

// ---------------------------------------------------------------------------
extern "C" void kernel_launch(void* const* d_in, const int* in_sizes, int n_in,
                              void* d_out, int out_size, void* d_ws,
                              size_t ws_size, hipStream_t stream) {
  const float* x = (const float*)d_in[0];
  const float* e = (const float*)d_in[1];
  const float* g = (const float*)d_in[2];
  float* out = (float*)d_out;
  char* wsb = (char*)d_ws;
  // ws layout (bytes):
  //   esq@0 (4K) | avg_rep@16384 (512K) | counts_rep@540672 (512K) |
  //   sd_rep@1064960 (8K) | xsq_rep@1073152 (8K) | ehi@1081344 (1M) |
  //   elo@+1M | dmap@3178496
  float* esq = (float*)wsb;
  float* avg_rep = (float*)(wsb + 16384);
  int* counts_rep = (int*)(wsb + 540672);
  float* sd_rep = (float*)(wsb + 1064960);
  float* xsq_rep = (float*)(wsb + 1073152);
  _Float16* ehi = (_Float16*)(wsb + 1081344);
  _Float16* elo = (_Float16*)(wsb + 1081344 + 1048576);
  float* dmap = (float*)(wsb + 3178496);

  // chunk rows so dmap (4 KB/row fp32) fits in the remaining workspace
  const size_t cap = (ws_size > 3178496) ? ws_size - 3178496 : 0;
  long long cr = (long long)(cap / 4096);
  cr = (cr / 128) * 128;
  if (cr > NTOT) cr = NTOT;
  if (cr < 128) cr = 128;
  const int chunk_rows = (int)cr;

  // zero all replicated accumulators (avg, counts, sd, xsq)
  hipMemsetAsync(wsb + 16384, 0, 1064960, stream);

  e_to_frag<<<256, 256, 0, stream>>>(e, ehi, elo);
  esq_kernel<<<256, 256, 0, stream>>>(e, esq);
  xsq_kernel<<<1024, 256, 0, stream>>>(x, xsq_rep);

  for (int n0 = 0; n0 < NTOT; n0 += chunk_rows) {
    const int rows = (NTOT - n0 < chunk_rows) ? (NTOT - n0) : chunk_rows;
    gemm_dmap<<<8 * (rows / 128), 256, 0, stream>>>(
        x + (size_t)n0 * DDIM, ehi, elo, esq, dmap);
    epi<<<rows / 32, 256, 0, stream>>>(
        e, dmap, g + (size_t)n0 * MDIM, out + (size_t)n0 * DDIM,
        avg_rep, counts_rep, sd_rep);
  }
  finalize<<<1, 1024, 0, stream>>>(avg_rep, counts_rep, sd_rep, xsq_rep, out);
}

// Round 14
// 214.265 us; speedup vs baseline: 1.2525x; 1.2525x over previous
//
#include <hip/hip_runtime.h>
#include <math.h>

// Problem constants (GumbelVectorQuantizer): B=16,T=2048,D=512,M=1024
#define NTOT 32768   // B*T
#define DDIM 512
#define MDIM 1024
#define QOFF 16777216  // quantized element count (output scalars follow)
#define NREP 32        // atomic-spread replicas

typedef _Float16 f16x8 __attribute__((ext_vector_type(8)));
typedef float    f32x4 __attribute__((ext_vector_type(4)));

// async global->LDS: per-LANE global src pointer, wave-uniform LDS dest base
__device__ __forceinline__ void gload_lds16(const void* g, void* l) {
  __builtin_amdgcn_global_load_lds(
      (const __attribute__((address_space(1))) void*)g,
      (__attribute__((address_space(3))) void*)l, 16, 0, 0);
}

// ---------------------------------------------------------------------------
// Pre-swizzle E into MFMA B-fragment order, fp16 hi/lo split; FUSED esq:
// each thread's 8-element fragment partial is atomically added to esq[m]
// (esq zeroed by host-side memset; order-invariant to ~1e-4, below the fp32
// GEMM noise already proven argmax-safe).
// Flat order: [mt(8)][ks(16)][ctg(8)][lane(64)][8 halves].
__global__ __launch_bounds__(256) void e_to_frag(const float* __restrict__ e,
                                                 _Float16* __restrict__ hi,
                                                 _Float16* __restrict__ lo,
                                                 float* __restrict__ esq) {
  const int tid = blockIdx.x * 256 + threadIdx.x;   // 65536 threads
  const int lane = tid & 63;
  const int F = tid >> 6;            // F = mt*128 + ks*8 + ctg
  const int mt = F >> 7;
  const int ks = (F >> 3) & 15;
  const int ctg = F & 7;
  const int m = mt * 128 + ctg * 16 + (lane & 15);
  const int k0 = ks * 32 + (lane >> 4) * 8;
  const float* src = e + (size_t)m * DDIM + k0;
  const float4 a = *(const float4*)src;
  const float4 b = *(const float4*)(src + 4);
  f16x8 vh, vl;
  vh[0] = (_Float16)a.x; vl[0] = (_Float16)(a.x - (float)vh[0]);
  vh[1] = (_Float16)a.y; vl[1] = (_Float16)(a.y - (float)vh[1]);
  vh[2] = (_Float16)a.z; vl[2] = (_Float16)(a.z - (float)vh[2]);
  vh[3] = (_Float16)a.w; vl[3] = (_Float16)(a.w - (float)vh[3]);
  vh[4] = (_Float16)b.x; vl[4] = (_Float16)(b.x - (float)vh[4]);
  vh[5] = (_Float16)b.y; vl[5] = (_Float16)(b.y - (float)vh[5]);
  vh[6] = (_Float16)b.z; vl[6] = (_Float16)(b.z - (float)vh[6]);
  vh[7] = (_Float16)b.w; vl[7] = (_Float16)(b.w - (float)vh[7]);
  *(f16x8*)(hi + (size_t)tid * 8) = vh;
  *(f16x8*)(lo + (size_t)tid * 8) = vl;
  const float es = ((a.x * a.x + a.y * a.y) + (a.z * a.z + a.w * a.w)) +
                   ((b.x * b.x + b.y * b.y) + (b.z * b.z + b.w * b.w));
  atomicAdd(&esq[m], es);
}

// ---------------------------------------------------------------------------
// GEMM: dmap' = 10 * X.E^T - 5*||e||^2 (m97 structure + XCD remap, verified
// ~963 TF effective).  r14: FUSED xsq -- the a0_/a1_ loads in COMPUTE cover
// each x element of the block's 128x512 panel exactly once (the XOR swizzle
// permutes {0,16,..,112} onto itself), so per-thread xs accumulation plus an
// mt==0 flush gives sum(x^2) for free (deletes the xsq kernel).
#define CVT1(RT, J, V)                                                         \
  Ah[RT][J] = (_Float16)(V);                                                   \
  Al[RT][J] = (_Float16)((V) - (float)Ah[RT][J]);
#define CVT8(RT, A0, A1)                                                       \
  CVT1(RT, 0, A0[0]) CVT1(RT, 1, A0[1]) CVT1(RT, 2, A0[2]) CVT1(RT, 3, A0[3]) \
  CVT1(RT, 4, A1[0]) CVT1(RT, 5, A1[1]) CVT1(RT, 6, A1[2]) CVT1(RT, 7, A1[3])

#define STAGE(AsP, BhP, BlP, KS)                                               \
  {                                                                            \
    _Pragma("unroll") for (int i_ = 0; i_ < 4; ++i_) {                         \
      const int row_ = (w * 4 + i_) * 8 + (lane >> 3);                         \
      const int cf_ = ((lane & 7) ^ (row_ & 7)) * 4;                           \
      gload_lds16(x + (size_t)(n0 + row_) * DDIM + (KS) * 32 + cf_,            \
                  (AsP) + (w * 4 + i_) * 1024);                                \
    }                                                                          \
    _Pragma("unroll") for (int i_ = 0; i_ < 2; ++i_) {                         \
      const size_t so_ =                                                       \
          (size_t)(mt * 16 + (KS)) * 8192 + (w * 2 + i_) * 1024 + lane * 16;   \
      gload_lds16((const char*)ehi + so_, (BhP) + (w * 2 + i_) * 1024);        \
      gload_lds16((const char*)elo + so_, (BlP) + (w * 2 + i_) * 1024);        \
    }                                                                          \
  }

#define COMPUTE(AsP, BhP, BlP)                                                 \
  {                                                                            \
    f16x8 Bhf[8], Blf[8];                                                      \
    _Pragma("unroll") for (int c_ = 0; c_ < 8; ++c_) {                         \
      Bhf[c_] = *(const f16x8*)((BhP) + c_ * 1024 + lane * 16);                \
      Blf[c_] = *(const f16x8*)((BlP) + c_ * 1024 + lane * 16);                \
    }                                                                          \
    f16x8 Ah[2], Al[2];                                                        \
    _Pragma("unroll") for (int rt_ = 0; rt_ < 2; ++rt_) {                      \
      const int row_ = w * 32 + rt_ * 16 + l15;                                \
      const int sw_ = (row_ & 7) << 4;                                         \
      const char* rb_ = (AsP) + row_ * 128;                                    \
      const f32x4 a0_ = *(const f32x4*)(rb_ + ((lg * 32) ^ sw_));              \
      const f32x4 a1_ = *(const f32x4*)(rb_ + ((lg * 32 + 16) ^ sw_));         \
      xs_acc += ((a0_[0] * a0_[0] + a0_[1] * a0_[1]) +                         \
                 (a0_[2] * a0_[2] + a0_[3] * a0_[3])) +                        \
                ((a1_[0] * a1_[0] + a1_[1] * a1_[1]) +                         \
                 (a1_[2] * a1_[2] + a1_[3] * a1_[3]));                         \
      CVT8(rt_, a0_, a1_)                                                      \
    }                                                                          \
    _Pragma("unroll") for (int c_ = 0; c_ < 8; ++c_)                           \
        _Pragma("unroll") for (int rt_ = 0; rt_ < 2; ++rt_)                    \
            acc[rt_][c_] = __builtin_amdgcn_mfma_f32_16x16x32_f16(             \
                Ah[rt_], Bhf[c_], acc[rt_][c_], 0, 0, 0);                      \
    _Pragma("unroll") for (int c_ = 0; c_ < 8; ++c_)                           \
        _Pragma("unroll") for (int rt_ = 0; rt_ < 2; ++rt_)                    \
            acc[rt_][c_] = __builtin_amdgcn_mfma_f32_16x16x32_f16(             \
                Al[rt_], Bhf[c_], acc[rt_][c_], 0, 0, 0);                      \
    _Pragma("unroll") for (int c_ = 0; c_ < 8; ++c_)                           \
        _Pragma("unroll") for (int rt_ = 0; rt_ < 2; ++rt_)                    \
            acc[rt_][c_] = __builtin_amdgcn_mfma_f32_16x16x32_f16(             \
                Ah[rt_], Blf[c_], acc[rt_][c_], 0, 0, 0);                      \
  }

__global__ __launch_bounds__(256, 2)
void gemm_dmap(const float* __restrict__ x, const _Float16* __restrict__ ehi,
               const _Float16* __restrict__ elo, const float* __restrict__ esq,
               float* __restrict__ dmap, float* __restrict__ xsq_rep) {
  __shared__ __align__(16) char smem[66048];
  char* const AsA = smem;              // A slab fp32 [128][32] = 16 KB
  char* const AsB = smem + 16384;
  char* const BhA = smem + 32768;      // B hi frag slab 8 KB
  char* const BhB = smem + 40960;
  char* const BlA = smem + 49152;      // B lo frag slab 8 KB
  char* const BlB = smem + 57344;
  float* const esqt = (float*)(smem + 65536);

  const int t = threadIdx.x;
  const int w = t >> 6;
  const int lane = t & 63;
  const int l15 = lane & 15;
  const int lg = lane >> 4;

  // XCD-aware remap (bijective only when rowblocks%8==0; else identity)
  int mt, nt;
  const int rowblocks = gridDim.x >> 3;
  if ((rowblocks & 7) == 0) {
    const int r = blockIdx.x & 7;        // ~XCD id (dispatch round-robin)
    const int q = blockIdx.x >> 3;
    mt = q & 7;
    nt = r + 8 * (q >> 3);
  } else {
    mt = blockIdx.x & 7;
    nt = blockIdx.x >> 3;
  }
  const int n0 = nt * 128;

  if (t < 128) esqt[t] = esq[mt * 128 + t];

  f32x4 acc[2][8];
#pragma unroll
  for (int rt = 0; rt < 2; ++rt)
#pragma unroll
    for (int c = 0; c < 8; ++c) acc[rt][c] = (f32x4){0.f, 0.f, 0.f, 0.f};
  float xs_acc = 0.f;

  STAGE(AsA, BhA, BlA, 0)
  __syncthreads();

  for (int kk = 0; kk < 8; ++kk) {
    const int ks = kk * 2;
    STAGE(AsB, BhB, BlB, ks + 1)
    COMPUTE(AsA, BhA, BlA)
    __syncthreads();
    if (ks + 2 < 16) STAGE(AsA, BhA, BlA, ks + 2)
    COMPUTE(AsB, BhB, BlB)
    __syncthreads();
  }

#pragma unroll
  for (int rt = 0; rt < 2; ++rt)
#pragma unroll
    for (int ct = 0; ct < 8; ++ct) {
      const float e5 = 5.f * esqt[ct * 16 + l15];
      float* dr = dmap + (size_t)(n0 + w * 32 + rt * 16 + lg * 4) * 1024 +
                  mt * 128 + ct * 16 + l15;
#pragma unroll
      for (int rg = 0; rg < 4; ++rg)
        dr[(size_t)rg * 1024] = 10.f * acc[rt][ct][rg] - e5;
    }

  // fused xsq: mt==0 blocks cover every row panel exactly once
  if (mt == 0) {
#pragma unroll
    for (int off = 32; off; off >>= 1) xs_acc += __shfl_xor(xs_acc, off);
    if (lane == 0) atomicAdd(&xsq_rep[(nt & (NREP - 1)) * 16], xs_acc);
  }
}

// ---------------------------------------------------------------------------
#define AMAX(V, MM)                                                            \
  { const float v_ = (V); const int m_ = (MM);                                 \
    if (v_ > bv || (v_ == bv && m_ < bi)) { bv = v_; bi = m_; } }
#define GMAXD(V, MM, DV)                                                       \
  { const float v_ = (V); const int m_ = (MM);                                 \
    if (v_ > gv || (v_ == gv && m_ < gi)) { gv = v_; gi = m_; dv = (DV); } }

// per-row work: argmax->counts_rep, softmax->cav, gumbel argmax->(gi,dv),
// gather emb[gi]->out, sd_wave += dmap'[n][gi]  (SSE identity, no x read)
#define ROWBODY(N)                                                             \
  {                                                                            \
    const int n_ = (N);                                                        \
    const float* Dr = dmap + (size_t)n_ * MDIM;                                \
    const float4* grow = (const float4*)(gum + (size_t)n_ * MDIM);             \
    const float4 q0 = grow[lane];                                              \
    const float4 q1 = grow[lane + 64];                                         \
    const float4 q2 = grow[lane + 128];                                        \
    const float4 q3 = grow[lane + 192];                                        \
    const float4 d0 = *(const float4*)&Dr[co];                                 \
    const float4 d1 = *(const float4*)&Dr[co + 256];                           \
    const float4 d2 = *(const float4*)&Dr[co + 512];                           \
    const float4 d3 = *(const float4*)&Dr[co + 768];                           \
    float bv = -3.402823466e+38f; int bi = 0;                                  \
    AMAX(d0.x, co + 0)   AMAX(d0.y, co + 1)   AMAX(d0.z, co + 2)   AMAX(d0.w, co + 3)   \
    AMAX(d1.x, co + 256) AMAX(d1.y, co + 257) AMAX(d1.z, co + 258) AMAX(d1.w, co + 259) \
    AMAX(d2.x, co + 512) AMAX(d2.y, co + 513) AMAX(d2.z, co + 514) AMAX(d2.w, co + 515) \
    AMAX(d3.x, co + 768) AMAX(d3.y, co + 769) AMAX(d3.z, co + 770) AMAX(d3.w, co + 771) \
    _Pragma("unroll") for (int off = 32; off; off >>= 1) {                     \
      const float ov = __shfl_xor(bv, off);                                    \
      const int oi = __shfl_xor(bi, off);                                      \
      if (ov > bv || (ov == bv && oi < bi)) { bv = ov; bi = oi; }              \
    }                                                                          \
    if (lane == 0) atomicAdd(&counts_rep[rep + bi], 1);                        \
    float4 p0, p1, p2, p3;                                                     \
    p0.x = __expf(d0.x - bv); p0.y = __expf(d0.y - bv);                        \
    p0.z = __expf(d0.z - bv); p0.w = __expf(d0.w - bv);                        \
    p1.x = __expf(d1.x - bv); p1.y = __expf(d1.y - bv);                        \
    p1.z = __expf(d1.z - bv); p1.w = __expf(d1.w - bv);                        \
    p2.x = __expf(d2.x - bv); p2.y = __expf(d2.y - bv);                        \
    p2.z = __expf(d2.z - bv); p2.w = __expf(d2.w - bv);                        \
    p3.x = __expf(d3.x - bv); p3.y = __expf(d3.y - bv);                        \
    p3.z = __expf(d3.z - bv); p3.w = __expf(d3.w - bv);                        \
    float ssum = (((p0.x + p0.y) + (p0.z + p0.w)) + ((p1.x + p1.y) + (p1.z + p1.w))) + \
                 (((p2.x + p2.y) + (p2.z + p2.w)) + ((p3.x + p3.y) + (p3.z + p3.w)));  \
    _Pragma("unroll") for (int off = 32; off; off >>= 1)                       \
        ssum += __shfl_xor(ssum, off);                                         \
    const float inv = 1.0f / ssum;                                             \
    cav0.x += p0.x * inv; cav0.y += p0.y * inv;                                \
    cav0.z += p0.z * inv; cav0.w += p0.w * inv;                                \
    cav1.x += p1.x * inv; cav1.y += p1.y * inv;                                \
    cav1.z += p1.z * inv; cav1.w += p1.w * inv;                                \
    cav2.x += p2.x * inv; cav2.y += p2.y * inv;                                \
    cav2.z += p2.z * inv; cav2.w += p2.w * inv;                                \
    cav3.x += p3.x * inv; cav3.y += p3.y * inv;                                \
    cav3.z += p3.z * inv; cav3.w += p3.w * inv;                                \
    float gv = -3.402823466e+38f, dv = 0.f; int gi = 0;                        \
    GMAXD(d0.x + q0.x, co + 0, d0.x)     GMAXD(d0.y + q0.y, co + 1, d0.y)      \
    GMAXD(d0.z + q0.z, co + 2, d0.z)     GMAXD(d0.w + q0.w, co + 3, d0.w)      \
    GMAXD(d1.x + q1.x, co + 256, d1.x)   GMAXD(d1.y + q1.y, co + 257, d1.y)    \
    GMAXD(d1.z + q1.z, co + 258, d1.z)   GMAXD(d1.w + q1.w, co + 259, d1.w)    \
    GMAXD(d2.x + q2.x, co + 512, d2.x)   GMAXD(d2.y + q2.y, co + 513, d2.y)    \
    GMAXD(d2.z + q2.z, co + 514, d2.z)   GMAXD(d2.w + q2.w, co + 515, d2.w)    \
    GMAXD(d3.x + q3.x, co + 768, d3.x)   GMAXD(d3.y + q3.y, co + 769, d3.y)    \
    GMAXD(d3.z + q3.z, co + 770, d3.z)   GMAXD(d3.w + q3.w, co + 771, d3.w)    \
    _Pragma("unroll") for (int off = 32; off; off >>= 1) {                     \
      const float ov = __shfl_xor(gv, off);                                    \
      const int oi = __shfl_xor(gi, off);                                      \
      const float od = __shfl_xor(dv, off);                                    \
      if (ov > gv || (ov == gv && oi < gi)) { gv = ov; gi = oi; dv = od; }     \
    }                                                                          \
    sd_wave += dv;                                                             \
    const float4* erow = (const float4*)(emb + (size_t)gi * DDIM);             \
    float4* orow = (float4*)(out + (size_t)n_ * DDIM);                         \
    orow[lane] = erow[lane];                                                   \
    orow[lane + 64] = erow[lane + 64];                                         \
  }

// Streaming epilogue: r11-verbatim (proven optimum over 6 variants):
// 1024 blocks x 4 waves x 8 rows/wave, natural regalloc, LDS combine,
// 32-way atomic spread, no-x algebra.
__global__ __launch_bounds__(256)
void epi(const float* __restrict__ emb, const float* __restrict__ dmap,
         const float* __restrict__ gum, float* __restrict__ out,
         float* __restrict__ avg_rep, int* __restrict__ counts_rep,
         float* __restrict__ sd_rep) {
  __shared__ float avg_s[MDIM];
  const int t = threadIdx.x;
  const int w = t >> 6;
  const int lane = t & 63;
  const int co = lane << 2;
  const int rep = (blockIdx.x & (NREP - 1)) * MDIM;  // this block's replica
  avg_s[t] = 0.f; avg_s[t + 256] = 0.f; avg_s[t + 512] = 0.f; avg_s[t + 768] = 0.f;
  __syncthreads();

  float4 cav0 = make_float4(0.f, 0.f, 0.f, 0.f);
  float4 cav1 = make_float4(0.f, 0.f, 0.f, 0.f);
  float4 cav2 = make_float4(0.f, 0.f, 0.f, 0.f);
  float4 cav3 = make_float4(0.f, 0.f, 0.f, 0.f);
  float sd_wave = 0.f;

  const int nb = blockIdx.x * 32 + w * 8;  // chunk-local row base (8 rows)
  for (int i = 0; i < 8; ++i) {
    ROWBODY(nb + i)
  }

  if (lane == 0) atomicAdd(&sd_rep[(blockIdx.x & (NREP - 1)) * 16], sd_wave);

  atomicAdd(&avg_s[co + 0], cav0.x);   atomicAdd(&avg_s[co + 1], cav0.y);
  atomicAdd(&avg_s[co + 2], cav0.z);   atomicAdd(&avg_s[co + 3], cav0.w);
  atomicAdd(&avg_s[co + 256], cav1.x); atomicAdd(&avg_s[co + 257], cav1.y);
  atomicAdd(&avg_s[co + 258], cav1.z); atomicAdd(&avg_s[co + 259], cav1.w);
  atomicAdd(&avg_s[co + 512], cav2.x); atomicAdd(&avg_s[co + 513], cav2.y);
  atomicAdd(&avg_s[co + 514], cav2.z); atomicAdd(&avg_s[co + 515], cav2.w);
  atomicAdd(&avg_s[co + 768], cav3.x); atomicAdd(&avg_s[co + 769], cav3.y);
  atomicAdd(&avg_s[co + 770], cav3.z); atomicAdd(&avg_s[co + 771], cav3.w);
  __syncthreads();
  atomicAdd(&avg_rep[rep + t], avg_s[t]);
  atomicAdd(&avg_rep[rep + t + 256], avg_s[t + 256]);
  atomicAdd(&avg_rep[rep + t + 512], avg_s[t + 512]);
  atomicAdd(&avg_rep[rep + t + 768], avg_s[t + 768]);
}

// ---------------------------------------------------------------------------
__global__ __launch_bounds__(1024)
void finalize(const float* __restrict__ avg_rep, const int* __restrict__ counts_rep,
              const float* __restrict__ sd_rep, const float* __restrict__ xsq_rep,
              float* __restrict__ out) {
  __shared__ float red[32];
  const int t = threadIdx.x;
  float q = 0.f; int c = 0;
#pragma unroll
  for (int r = 0; r < NREP; ++r) {
    q += avg_rep[r * MDIM + t];
    c += counts_rep[r * MDIM + t];
  }
  const float invN = 1.f / 32768.f;
  const float p = (float)c * invN;
  float a = p * log2f(p + 1e-10f);
  const float qq = q * invN;
  float b = qq * log2f(qq + 1e-10f);
#pragma unroll
  for (int off = 32; off; off >>= 1) {
    a += __shfl_xor(a, off);
    b += __shfl_xor(b, off);
  }
  const int wv = t >> 6, ln = t & 63;
  if (ln == 0) { red[wv] = a; red[wv + 16] = b; }
  __syncthreads();
  if (t == 0) {
    float sa = 0.f, sb = 0.f;
#pragma unroll
    for (int i = 0; i < 16; ++i) { sa += red[i]; sb += red[i + 16]; }
    float sd = 0.f, xs = 0.f;
#pragma unroll
    for (int r = 0; r < NREP; ++r) { sd += sd_rep[r * 16]; xs += xsq_rep[r * 16]; }
    out[QOFF + 0] = -sa;                                // code_perplexity
    out[QOFF + 1] = -sb;                                // prob_perplexity
    const float sse = xs - sd * 0.2f;                   // SSE identity
    out[QOFF + 2] = sse * (1.f / (32768.f * 512.f));    // commitment_loss
  }
}

// ---------------------------------------------------------------------------
extern "C" void kernel_launch(void* const* d_in, const int* in_sizes, int n_in,
                              void* d_out, int out_size, void* d_ws,
                              size_t ws_size, hipStream_t stream) {
  const float* x = (const float*)d_in[0];
  const float* e = (const float*)d_in[1];
  const float* g = (const float*)d_in[2];
  float* out = (float*)d_out;
  char* wsb = (char*)d_ws;
  // ws layout (bytes):
  //   esq@0 (4K) | avg_rep@16384 (128K) | counts_rep@147456 (128K) |
  //   sd_rep@278528 (2K) | xsq_rep@280576 (2K) | ehi@282624 (1M) |
  //   elo@+1M | dmap@2379776
  float* esq = (float*)wsb;
  float* avg_rep = (float*)(wsb + 16384);
  int* counts_rep = (int*)(wsb + 147456);
  float* sd_rep = (float*)(wsb + 278528);
  float* xsq_rep = (float*)(wsb + 280576);
  _Float16* ehi = (_Float16*)(wsb + 282624);
  _Float16* elo = (_Float16*)(wsb + 282624 + 1048576);
  float* dmap = (float*)(wsb + 2379776);

  // chunk rows so dmap (4 KB/row fp32) fits in the remaining workspace
  const size_t cap = (ws_size > 2379776) ? ws_size - 2379776 : 0;
  long long cr = (long long)(cap / 4096);
  cr = (cr / 128) * 128;
  if (cr > NTOT) cr = NTOT;
  if (cr < 128) cr = 128;
  const int chunk_rows = (int)cr;

  // zero esq + all replicated accumulators (avg, counts, sd, xsq)
  hipMemsetAsync(wsb, 0, 282624, stream);

  e_to_frag<<<256, 256, 0, stream>>>(e, ehi, elo, esq);

  for (int n0 = 0; n0 < NTOT; n0 += chunk_rows) {
    const int rows = (NTOT - n0 < chunk_rows) ? (NTOT - n0) : chunk_rows;
    gemm_dmap<<<8 * (rows / 128), 256, 0, stream>>>(
        x + (size_t)n0 * DDIM, ehi, elo, esq, dmap, xsq_rep);
    epi<<<rows / 32, 256, 0, stream>>>(
        e, dmap, g + (size_t)n0 * MDIM, out + (size_t)n0 * DDIM,
        avg_rep, counts_rep, sd_rep);
  }
  finalize<<<1, 1024, 0, stream>>>(avg_rep, counts_rep, sd_rep, xsq_rep, out);
}

// Round 15
// 211.432 us; speedup vs baseline: 1.2693x; 1.0134x over previous
//
#include <hip/hip_runtime.h>
#include <math.h>

// Problem constants (GumbelVectorQuantizer): B=16,T=2048,D=512,M=1024
#define NTOT 32768   // B*T
#define DDIM 512
#define MDIM 1024
#define QOFF 16777216  // quantized element count (output scalars follow)
#define NREP 32        // atomic-spread replicas

typedef _Float16 f16x8 __attribute__((ext_vector_type(8)));
typedef float    f32x4 __attribute__((ext_vector_type(4)));

// async global->LDS: per-LANE global src pointer, wave-uniform LDS dest base
__device__ __forceinline__ void gload_lds16(const void* g, void* l) {
  __builtin_amdgcn_global_load_lds(
      (const __attribute__((address_space(1))) void*)g,
      (__attribute__((address_space(3))) void*)l, 16, 0, 0);
}

// ---------------------------------------------------------------------------
// Pre-swizzle E into MFMA B-fragment order, fp16 hi/lo split; FUSED esq
// (r14-verified: atomic partials to esq[m], order-invariant, argmax-safe).
// Flat order: [mt(8)][ks(16)][ctg(8)][lane(64)][8 halves].
__global__ __launch_bounds__(256) void e_to_frag(const float* __restrict__ e,
                                                 _Float16* __restrict__ hi,
                                                 _Float16* __restrict__ lo,
                                                 float* __restrict__ esq) {
  const int tid = blockIdx.x * 256 + threadIdx.x;   // 65536 threads
  const int lane = tid & 63;
  const int F = tid >> 6;            // F = mt*128 + ks*8 + ctg
  const int mt = F >> 7;
  const int ks = (F >> 3) & 15;
  const int ctg = F & 7;
  const int m = mt * 128 + ctg * 16 + (lane & 15);
  const int k0 = ks * 32 + (lane >> 4) * 8;
  const float* src = e + (size_t)m * DDIM + k0;
  const float4 a = *(const float4*)src;
  const float4 b = *(const float4*)(src + 4);
  f16x8 vh, vl;
  vh[0] = (_Float16)a.x; vl[0] = (_Float16)(a.x - (float)vh[0]);
  vh[1] = (_Float16)a.y; vl[1] = (_Float16)(a.y - (float)vh[1]);
  vh[2] = (_Float16)a.z; vl[2] = (_Float16)(a.z - (float)vh[2]);
  vh[3] = (_Float16)a.w; vl[3] = (_Float16)(a.w - (float)vh[3]);
  vh[4] = (_Float16)b.x; vl[4] = (_Float16)(b.x - (float)vh[4]);
  vh[5] = (_Float16)b.y; vl[5] = (_Float16)(b.y - (float)vh[5]);
  vh[6] = (_Float16)b.z; vl[6] = (_Float16)(b.z - (float)vh[6]);
  vh[7] = (_Float16)b.w; vl[7] = (_Float16)(b.w - (float)vh[7]);
  *(f16x8*)(hi + (size_t)tid * 8) = vh;
  *(f16x8*)(lo + (size_t)tid * 8) = vl;
  const float es = ((a.x * a.x + a.y * a.y) + (a.z * a.z + a.w * a.w)) +
                   ((b.x * b.x + b.y * b.y) + (b.z * b.z + b.w * b.w));
  atomicAdd(&esq[m], es);
}

// ---------------------------------------------------------------------------
// GEMM: dmap' = 10 * X.E^T - 5*||e||^2 (m97 structure + XCD remap).
// r15: xs accumulation PREDICATED on mt==0 (block-uniform branch) -- only the
// 64 blocks that flush pay the VALU cost (r14 lesson: unconditional xs_acc
// cost ~+23% gemm time for work 7/8 of blocks discarded).
#define CVT1(RT, J, V)                                                         \
  Ah[RT][J] = (_Float16)(V);                                                   \
  Al[RT][J] = (_Float16)((V) - (float)Ah[RT][J]);
#define CVT8(RT, A0, A1)                                                       \
  CVT1(RT, 0, A0[0]) CVT1(RT, 1, A0[1]) CVT1(RT, 2, A0[2]) CVT1(RT, 3, A0[3]) \
  CVT1(RT, 4, A1[0]) CVT1(RT, 5, A1[1]) CVT1(RT, 6, A1[2]) CVT1(RT, 7, A1[3])

#define STAGE(AsP, BhP, BlP, KS)                                               \
  {                                                                            \
    _Pragma("unroll") for (int i_ = 0; i_ < 4; ++i_) {                         \
      const int row_ = (w * 4 + i_) * 8 + (lane >> 3);                         \
      const int cf_ = ((lane & 7) ^ (row_ & 7)) * 4;                           \
      gload_lds16(x + (size_t)(n0 + row_) * DDIM + (KS) * 32 + cf_,            \
                  (AsP) + (w * 4 + i_) * 1024);                                \
    }                                                                          \
    _Pragma("unroll") for (int i_ = 0; i_ < 2; ++i_) {                         \
      const size_t so_ =                                                       \
          (size_t)(mt * 16 + (KS)) * 8192 + (w * 2 + i_) * 1024 + lane * 16;   \
      gload_lds16((const char*)ehi + so_, (BhP) + (w * 2 + i_) * 1024);        \
      gload_lds16((const char*)elo + so_, (BlP) + (w * 2 + i_) * 1024);        \
    }                                                                          \
  }

#define COMPUTE(AsP, BhP, BlP)                                                 \
  {                                                                            \
    f16x8 Bhf[8], Blf[8];                                                      \
    _Pragma("unroll") for (int c_ = 0; c_ < 8; ++c_) {                         \
      Bhf[c_] = *(const f16x8*)((BhP) + c_ * 1024 + lane * 16);                \
      Blf[c_] = *(const f16x8*)((BlP) + c_ * 1024 + lane * 16);                \
    }                                                                          \
    f16x8 Ah[2], Al[2];                                                        \
    _Pragma("unroll") for (int rt_ = 0; rt_ < 2; ++rt_) {                      \
      const int row_ = w * 32 + rt_ * 16 + l15;                                \
      const int sw_ = (row_ & 7) << 4;                                         \
      const char* rb_ = (AsP) + row_ * 128;                                    \
      const f32x4 a0_ = *(const f32x4*)(rb_ + ((lg * 32) ^ sw_));              \
      const f32x4 a1_ = *(const f32x4*)(rb_ + ((lg * 32 + 16) ^ sw_));         \
      if (doxs) {                                                              \
        xs_acc += ((a0_[0] * a0_[0] + a0_[1] * a0_[1]) +                       \
                   (a0_[2] * a0_[2] + a0_[3] * a0_[3])) +                      \
                  ((a1_[0] * a1_[0] + a1_[1] * a1_[1]) +                       \
                   (a1_[2] * a1_[2] + a1_[3] * a1_[3]));                       \
      }                                                                        \
      CVT8(rt_, a0_, a1_)                                                      \
    }                                                                          \
    _Pragma("unroll") for (int c_ = 0; c_ < 8; ++c_)                           \
        _Pragma("unroll") for (int rt_ = 0; rt_ < 2; ++rt_)                    \
            acc[rt_][c_] = __builtin_amdgcn_mfma_f32_16x16x32_f16(             \
                Ah[rt_], Bhf[c_], acc[rt_][c_], 0, 0, 0);                      \
    _Pragma("unroll") for (int c_ = 0; c_ < 8; ++c_)                           \
        _Pragma("unroll") for (int rt_ = 0; rt_ < 2; ++rt_)                    \
            acc[rt_][c_] = __builtin_amdgcn_mfma_f32_16x16x32_f16(             \
                Al[rt_], Bhf[c_], acc[rt_][c_], 0, 0, 0);                      \
    _Pragma("unroll") for (int c_ = 0; c_ < 8; ++c_)                           \
        _Pragma("unroll") for (int rt_ = 0; rt_ < 2; ++rt_)                    \
            acc[rt_][c_] = __builtin_amdgcn_mfma_f32_16x16x32_f16(             \
                Ah[rt_], Blf[c_], acc[rt_][c_], 0, 0, 0);                      \
  }

__global__ __launch_bounds__(256, 2)
void gemm_dmap(const float* __restrict__ x, const _Float16* __restrict__ ehi,
               const _Float16* __restrict__ elo, const float* __restrict__ esq,
               float* __restrict__ dmap, float* __restrict__ xsq_rep) {
  __shared__ __align__(16) char smem[66048];
  char* const AsA = smem;              // A slab fp32 [128][32] = 16 KB
  char* const AsB = smem + 16384;
  char* const BhA = smem + 32768;      // B hi frag slab 8 KB
  char* const BhB = smem + 40960;
  char* const BlA = smem + 49152;      // B lo frag slab 8 KB
  char* const BlB = smem + 57344;
  float* const esqt = (float*)(smem + 65536);

  const int t = threadIdx.x;
  const int w = t >> 6;
  const int lane = t & 63;
  const int l15 = lane & 15;
  const int lg = lane >> 4;

  // XCD-aware remap (bijective only when rowblocks%8==0; else identity)
  int mt, nt;
  const int rowblocks = gridDim.x >> 3;
  if ((rowblocks & 7) == 0) {
    const int r = blockIdx.x & 7;        // ~XCD id (dispatch round-robin)
    const int q = blockIdx.x >> 3;
    mt = q & 7;
    nt = r + 8 * (q >> 3);
  } else {
    mt = blockIdx.x & 7;
    nt = blockIdx.x >> 3;
  }
  const int n0 = nt * 128;
  const bool doxs = (mt == 0);   // only mt==0 blocks accumulate/flush xsq

  if (t < 128) esqt[t] = esq[mt * 128 + t];

  f32x4 acc[2][8];
#pragma unroll
  for (int rt = 0; rt < 2; ++rt)
#pragma unroll
    for (int c = 0; c < 8; ++c) acc[rt][c] = (f32x4){0.f, 0.f, 0.f, 0.f};
  float xs_acc = 0.f;

  STAGE(AsA, BhA, BlA, 0)
  __syncthreads();

  for (int kk = 0; kk < 8; ++kk) {
    const int ks = kk * 2;
    STAGE(AsB, BhB, BlB, ks + 1)
    COMPUTE(AsA, BhA, BlA)
    __syncthreads();
    if (ks + 2 < 16) STAGE(AsA, BhA, BlA, ks + 2)
    COMPUTE(AsB, BhB, BlB)
    __syncthreads();
  }

#pragma unroll
  for (int rt = 0; rt < 2; ++rt)
#pragma unroll
    for (int ct = 0; ct < 8; ++ct) {
      const float e5 = 5.f * esqt[ct * 16 + l15];
      float* dr = dmap + (size_t)(n0 + w * 32 + rt * 16 + lg * 4) * 1024 +
                  mt * 128 + ct * 16 + l15;
#pragma unroll
      for (int rg = 0; rg < 4; ++rg)
        dr[(size_t)rg * 1024] = 10.f * acc[rt][ct][rg] - e5;
    }

  // fused xsq: mt==0 blocks cover every row panel exactly once
  if (doxs) {
#pragma unroll
    for (int off = 32; off; off >>= 1) xs_acc += __shfl_xor(xs_acc, off);
    if (lane == 0) atomicAdd(&xsq_rep[(nt & (NREP - 1)) * 16], xs_acc);
  }
}

// ---------------------------------------------------------------------------
#define AMAX(V, MM)                                                            \
  { const float v_ = (V); const int m_ = (MM);                                 \
    if (v_ > bv || (v_ == bv && m_ < bi)) { bv = v_; bi = m_; } }
#define GMAXD(V, MM, DV)                                                       \
  { const float v_ = (V); const int m_ = (MM);                                 \
    if (v_ > gv || (v_ == gv && m_ < gi)) { gv = v_; gi = m_; dv = (DV); } }

// per-row work: argmax->counts_rep, softmax->cav, gumbel argmax->(gi,dv),
// gather emb[gi]->out, sd_wave += dmap'[n][gi]  (SSE identity, no x read)
#define ROWBODY(N)                                                             \
  {                                                                            \
    const int n_ = (N);                                                        \
    const float* Dr = dmap + (size_t)n_ * MDIM;                                \
    const float4* grow = (const float4*)(gum + (size_t)n_ * MDIM);             \
    const float4 q0 = grow[lane];                                              \
    const float4 q1 = grow[lane + 64];                                         \
    const float4 q2 = grow[lane + 128];                                        \
    const float4 q3 = grow[lane + 192];                                        \
    const float4 d0 = *(const float4*)&Dr[co];                                 \
    const float4 d1 = *(const float4*)&Dr[co + 256];                           \
    const float4 d2 = *(const float4*)&Dr[co + 512];                           \
    const float4 d3 = *(const float4*)&Dr[co + 768];                           \
    float bv = -3.402823466e+38f; int bi = 0;                                  \
    AMAX(d0.x, co + 0)   AMAX(d0.y, co + 1)   AMAX(d0.z, co + 2)   AMAX(d0.w, co + 3)   \
    AMAX(d1.x, co + 256) AMAX(d1.y, co + 257) AMAX(d1.z, co + 258) AMAX(d1.w, co + 259) \
    AMAX(d2.x, co + 512) AMAX(d2.y, co + 513) AMAX(d2.z, co + 514) AMAX(d2.w, co + 515) \
    AMAX(d3.x, co + 768) AMAX(d3.y, co + 769) AMAX(d3.z, co + 770) AMAX(d3.w, co + 771) \
    _Pragma("unroll") for (int off = 32; off; off >>= 1) {                     \
      const float ov = __shfl_xor(bv, off);                                    \
      const int oi = __shfl_xor(bi, off);                                      \
      if (ov > bv || (ov == bv && oi < bi)) { bv = ov; bi = oi; }              \
    }                                                                          \
    if (lane == 0) atomicAdd(&counts_rep[rep + bi], 1);                        \
    float4 p0, p1, p2, p3;                                                     \
    p0.x = __expf(d0.x - bv); p0.y = __expf(d0.y - bv);                        \
    p0.z = __expf(d0.z - bv); p0.w = __expf(d0.w - bv);                        \
    p1.x = __expf(d1.x - bv); p1.y = __expf(d1.y - bv);                        \
    p1.z = __expf(d1.z - bv); p1.w = __expf(d1.w - bv);                        \
    p2.x = __expf(d2.x - bv); p2.y = __expf(d2.y - bv);                        \
    p2.z = __expf(d2.z - bv); p2.w = __expf(d2.w - bv);                        \
    p3.x = __expf(d3.x - bv); p3.y = __expf(d3.y - bv);                        \
    p3.z = __expf(d3.z - bv); p3.w = __expf(d3.w - bv);                        \
    float ssum = (((p0.x + p0.y) + (p0.z + p0.w)) + ((p1.x + p1.y) + (p1.z + p1.w))) + \
                 (((p2.x + p2.y) + (p2.z + p2.w)) + ((p3.x + p3.y) + (p3.z + p3.w)));  \
    _Pragma("unroll") for (int off = 32; off; off >>= 1)                       \
        ssum += __shfl_xor(ssum, off);                                         \
    const float inv = 1.0f / ssum;                                             \
    cav0.x += p0.x * inv; cav0.y += p0.y * inv;                                \
    cav0.z += p0.z * inv; cav0.w += p0.w * inv;                                \
    cav1.x += p1.x * inv; cav1.y += p1.y * inv;                                \
    cav1.z += p1.z * inv; cav1.w += p1.w * inv;                                \
    cav2.x += p2.x * inv; cav2.y += p2.y * inv;                                \
    cav2.z += p2.z * inv; cav2.w += p2.w * inv;                                \
    cav3.x += p3.x * inv; cav3.y += p3.y * inv;                                \
    cav3.z += p3.z * inv; cav3.w += p3.w * inv;                                \
    float gv = -3.402823466e+38f, dv = 0.f; int gi = 0;                        \
    GMAXD(d0.x + q0.x, co + 0, d0.x)     GMAXD(d0.y + q0.y, co + 1, d0.y)      \
    GMAXD(d0.z + q0.z, co + 2, d0.z)     GMAXD(d0.w + q0.w, co + 3, d0.w)      \
    GMAXD(d1.x + q1.x, co + 256, d1.x)   GMAXD(d1.y + q1.y, co + 257, d1.y)    \
    GMAXD(d1.z + q1.z, co + 258, d1.z)   GMAXD(d1.w + q1.w, co + 259, d1.w)    \
    GMAXD(d2.x + q2.x, co + 512, d2.x)   GMAXD(d2.y + q2.y, co + 513, d2.y)    \
    GMAXD(d2.z + q2.z, co + 514, d2.z)   GMAXD(d2.w + q2.w, co + 515, d2.w)    \
    GMAXD(d3.x + q3.x, co + 768, d3.x)   GMAXD(d3.y + q3.y, co + 769, d3.y)    \
    GMAXD(d3.z + q3.z, co + 770, d3.z)   GMAXD(d3.w + q3.w, co + 771, d3.w)    \
    _Pragma("unroll") for (int off = 32; off; off >>= 1) {                     \
      const float ov = __shfl_xor(gv, off);                                    \
      const int oi = __shfl_xor(gi, off);                                      \
      const float od = __shfl_xor(dv, off);                                    \
      if (ov > gv || (ov == gv && oi < gi)) { gv = ov; gi = oi; dv = od; }     \
    }                                                                          \
    sd_wave += dv;                                                             \
    const float4* erow = (const float4*)(emb + (size_t)gi * DDIM);             \
    float4* orow = (float4*)(out + (size_t)n_ * DDIM);                         \
    orow[lane] = erow[lane];                                                   \
    orow[lane + 64] = erow[lane + 64];                                         \
  }

// Streaming epilogue: r11-verbatim (proven optimum over 7 variants):
// 1024 blocks x 4 waves x 8 rows/wave, natural regalloc, LDS combine,
// 32-way atomic spread, no-x algebra.
__global__ __launch_bounds__(256)
void epi(const float* __restrict__ emb, const float* __restrict__ dmap,
         const float* __restrict__ gum, float* __restrict__ out,
         float* __restrict__ avg_rep, int* __restrict__ counts_rep,
         float* __restrict__ sd_rep) {
  __shared__ float avg_s[MDIM];
  const int t = threadIdx.x;
  const int w = t >> 6;
  const int lane = t & 63;
  const int co = lane << 2;
  const int rep = (blockIdx.x & (NREP - 1)) * MDIM;  // this block's replica
  avg_s[t] = 0.f; avg_s[t + 256] = 0.f; avg_s[t + 512] = 0.f; avg_s[t + 768] = 0.f;
  __syncthreads();

  float4 cav0 = make_float4(0.f, 0.f, 0.f, 0.f);
  float4 cav1 = make_float4(0.f, 0.f, 0.f, 0.f);
  float4 cav2 = make_float4(0.f, 0.f, 0.f, 0.f);
  float4 cav3 = make_float4(0.f, 0.f, 0.f, 0.f);
  float sd_wave = 0.f;

  const int nb = blockIdx.x * 32 + w * 8;  // chunk-local row base (8 rows)
  for (int i = 0; i < 8; ++i) {
    ROWBODY(nb + i)
  }

  if (lane == 0) atomicAdd(&sd_rep[(blockIdx.x & (NREP - 1)) * 16], sd_wave);

  atomicAdd(&avg_s[co + 0], cav0.x);   atomicAdd(&avg_s[co + 1], cav0.y);
  atomicAdd(&avg_s[co + 2], cav0.z);   atomicAdd(&avg_s[co + 3], cav0.w);
  atomicAdd(&avg_s[co + 256], cav1.x); atomicAdd(&avg_s[co + 257], cav1.y);
  atomicAdd(&avg_s[co + 258], cav1.z); atomicAdd(&avg_s[co + 259], cav1.w);
  atomicAdd(&avg_s[co + 512], cav2.x); atomicAdd(&avg_s[co + 513], cav2.y);
  atomicAdd(&avg_s[co + 514], cav2.z); atomicAdd(&avg_s[co + 515], cav2.w);
  atomicAdd(&avg_s[co + 768], cav3.x); atomicAdd(&avg_s[co + 769], cav3.y);
  atomicAdd(&avg_s[co + 770], cav3.z); atomicAdd(&avg_s[co + 771], cav3.w);
  __syncthreads();
  atomicAdd(&avg_rep[rep + t], avg_s[t]);
  atomicAdd(&avg_rep[rep + t + 256], avg_s[t + 256]);
  atomicAdd(&avg_rep[rep + t + 512], avg_s[t + 512]);
  atomicAdd(&avg_rep[rep + t + 768], avg_s[t + 768]);
}

// ---------------------------------------------------------------------------
__global__ __launch_bounds__(1024)
void finalize(const float* __restrict__ avg_rep, const int* __restrict__ counts_rep,
              const float* __restrict__ sd_rep, const float* __restrict__ xsq_rep,
              float* __restrict__ out) {
  __shared__ float red[32];
  const int t = threadIdx.x;
  float q = 0.f; int c = 0;
#pragma unroll
  for (int r = 0; r < NREP; ++r) {
    q += avg_rep[r * MDIM + t];
    c += counts_rep[r * MDIM + t];
  }
  const float invN = 1.f / 32768.f;
  const float p = (float)c * invN;
  float a = p * log2f(p + 1e-10f);
  const float qq = q * invN;
  float b = qq * log2f(qq + 1e-10f);
#pragma unroll
  for (int off = 32; off; off >>= 1) {
    a += __shfl_xor(a, off);
    b += __shfl_xor(b, off);
  }
  const int wv = t >> 6, ln = t & 63;
  if (ln == 0) { red[wv] = a; red[wv + 16] = b; }
  __syncthreads();
  if (t == 0) {
    float sa = 0.f, sb = 0.f;
#pragma unroll
    for (int i = 0; i < 16; ++i) { sa += red[i]; sb += red[i + 16]; }
    float sd = 0.f, xs = 0.f;
#pragma unroll
    for (int r = 0; r < NREP; ++r) { sd += sd_rep[r * 16]; xs += xsq_rep[r * 16]; }
    out[QOFF + 0] = -sa;                                // code_perplexity
    out[QOFF + 1] = -sb;                                // prob_perplexity
    const float sse = xs - sd * 0.2f;                   // SSE identity
    out[QOFF + 2] = sse * (1.f / (32768.f * 512.f));    // commitment_loss
  }
}

// ---------------------------------------------------------------------------
extern "C" void kernel_launch(void* const* d_in, const int* in_sizes, int n_in,
                              void* d_out, int out_size, void* d_ws,
                              size_t ws_size, hipStream_t stream) {
  const float* x = (const float*)d_in[0];
  const float* e = (const float*)d_in[1];
  const float* g = (const float*)d_in[2];
  float* out = (float*)d_out;
  char* wsb = (char*)d_ws;
  // ws layout (bytes):
  //   esq@0 (4K) | avg_rep@16384 (128K) | counts_rep@147456 (128K) |
  //   sd_rep@278528 (2K) | xsq_rep@280576 (2K) | ehi@282624 (1M) |
  //   elo@+1M | dmap@2379776
  float* esq = (float*)wsb;
  float* avg_rep = (float*)(wsb + 16384);
  int* counts_rep = (int*)(wsb + 147456);
  float* sd_rep = (float*)(wsb + 278528);
  float* xsq_rep = (float*)(wsb + 280576);
  _Float16* ehi = (_Float16*)(wsb + 282624);
  _Float16* elo = (_Float16*)(wsb + 282624 + 1048576);
  float* dmap = (float*)(wsb + 2379776);

  // chunk rows so dmap (4 KB/row fp32) fits in the remaining workspace
  const size_t cap = (ws_size > 2379776) ? ws_size - 2379776 : 0;
  long long cr = (long long)(cap / 4096);
  cr = (cr / 128) * 128;
  if (cr > NTOT) cr = NTOT;
  if (cr < 128) cr = 128;
  const int chunk_rows = (int)cr;

  // zero esq + all replicated accumulators (avg, counts, sd, xsq)
  hipMemsetAsync(wsb, 0, 282624, stream);

  e_to_frag<<<256, 256, 0, stream>>>(e, ehi, elo, esq);

  for (int n0 = 0; n0 < NTOT; n0 += chunk_rows) {
    const int rows = (NTOT - n0 < chunk_rows) ? (NTOT - n0) : chunk_rows;
    gemm_dmap<<<8 * (rows / 128), 256, 0, stream>>>(
        x + (size_t)n0 * DDIM, ehi, elo, esq, dmap, xsq_rep);
    epi<<<rows / 32, 256, 0, stream>>>(
        e, dmap, g + (size_t)n0 * MDIM, out + (size_t)n0 * DDIM,
        avg_rep, counts_rep, sd_rep);
  }
  finalize<<<1, 1024, 0, stream>>>(avg_rep, counts_rep, sd_rep, xsq_rep, out);
}

// Round 16
// 202.425 us; speedup vs baseline: 1.3258x; 1.0445x over previous
//
#include <hip/hip_runtime.h>
#include <math.h>

// Problem constants (GumbelVectorQuantizer): B=16,T=2048,D=512,M=1024
#define NTOT 32768   // B*T
#define DDIM 512
#define MDIM 1024
#define QOFF 16777216  // quantized element count (output scalars follow)
#define NREP 32        // atomic-spread replicas

typedef _Float16 f16x8 __attribute__((ext_vector_type(8)));
typedef float    f32x4 __attribute__((ext_vector_type(4)));

// async global->LDS: per-LANE global src pointer, wave-uniform LDS dest base
__device__ __forceinline__ void gload_lds16(const void* g, void* l) {
  __builtin_amdgcn_global_load_lds(
      (const __attribute__((address_space(1))) void*)g,
      (__attribute__((address_space(3))) void*)l, 16, 0, 0);
}

// ---------------------------------------------------------------------------
// Pre-swizzle E into MFMA B-fragment order, fp16 hi/lo split; FUSED esq
// (r14-verified free: atomic partials to esq[m], order-invariant, argmax-safe).
// Flat order: [mt(8)][ks(16)][ctg(8)][lane(64)][8 halves].
__global__ __launch_bounds__(256) void e_to_frag(const float* __restrict__ e,
                                                 _Float16* __restrict__ hi,
                                                 _Float16* __restrict__ lo,
                                                 float* __restrict__ esq) {
  const int tid = blockIdx.x * 256 + threadIdx.x;   // 65536 threads
  const int lane = tid & 63;
  const int F = tid >> 6;            // F = mt*128 + ks*8 + ctg
  const int mt = F >> 7;
  const int ks = (F >> 3) & 15;
  const int ctg = F & 7;
  const int m = mt * 128 + ctg * 16 + (lane & 15);
  const int k0 = ks * 32 + (lane >> 4) * 8;
  const float* src = e + (size_t)m * DDIM + k0;
  const float4 a = *(const float4*)src;
  const float4 b = *(const float4*)(src + 4);
  f16x8 vh, vl;
  vh[0] = (_Float16)a.x; vl[0] = (_Float16)(a.x - (float)vh[0]);
  vh[1] = (_Float16)a.y; vl[1] = (_Float16)(a.y - (float)vh[1]);
  vh[2] = (_Float16)a.z; vl[2] = (_Float16)(a.z - (float)vh[2]);
  vh[3] = (_Float16)a.w; vl[3] = (_Float16)(a.w - (float)vh[3]);
  vh[4] = (_Float16)b.x; vl[4] = (_Float16)(b.x - (float)vh[4]);
  vh[5] = (_Float16)b.y; vl[5] = (_Float16)(b.y - (float)vh[5]);
  vh[6] = (_Float16)b.z; vl[6] = (_Float16)(b.z - (float)vh[6]);
  vh[7] = (_Float16)b.w; vl[7] = (_Float16)(b.w - (float)vh[7]);
  *(f16x8*)(hi + (size_t)tid * 8) = vh;
  *(f16x8*)(lo + (size_t)tid * 8) = vl;
  const float es = ((a.x * a.x + a.y * a.y) + (a.z * a.z + a.w * a.w)) +
                   ((b.x * b.x + b.y * b.y) + (b.z * b.z + b.w * b.w));
  atomicAdd(&esq[m], es);
}

// ---------------------------------------------------------------------------
// GEMM: dmap' = 10 * X.E^T - 5*||e||^2.  r16: reverted to r11-byte-identical
// (no xs accumulation anywhere -- r14/r15 lesson: instruction-level fusion of
// the x^2 sum cost 20-25 us of MFMA issue rate even when predicated).
#define CVT1(RT, J, V)                                                         \
  Ah[RT][J] = (_Float16)(V);                                                   \
  Al[RT][J] = (_Float16)((V) - (float)Ah[RT][J]);
#define CVT8(RT, A0, A1)                                                       \
  CVT1(RT, 0, A0[0]) CVT1(RT, 1, A0[1]) CVT1(RT, 2, A0[2]) CVT1(RT, 3, A0[3]) \
  CVT1(RT, 4, A1[0]) CVT1(RT, 5, A1[1]) CVT1(RT, 6, A1[2]) CVT1(RT, 7, A1[3])

#define STAGE(AsP, BhP, BlP, KS)                                               \
  {                                                                            \
    _Pragma("unroll") for (int i_ = 0; i_ < 4; ++i_) {                         \
      const int row_ = (w * 4 + i_) * 8 + (lane >> 3);                         \
      const int cf_ = ((lane & 7) ^ (row_ & 7)) * 4;                           \
      gload_lds16(x + (size_t)(n0 + row_) * DDIM + (KS) * 32 + cf_,            \
                  (AsP) + (w * 4 + i_) * 1024);                                \
    }                                                                          \
    _Pragma("unroll") for (int i_ = 0; i_ < 2; ++i_) {                         \
      const size_t so_ =                                                       \
          (size_t)(mt * 16 + (KS)) * 8192 + (w * 2 + i_) * 1024 + lane * 16;   \
      gload_lds16((const char*)ehi + so_, (BhP) + (w * 2 + i_) * 1024);        \
      gload_lds16((const char*)elo + so_, (BlP) + (w * 2 + i_) * 1024);        \
    }                                                                          \
  }

#define COMPUTE(AsP, BhP, BlP)                                                 \
  {                                                                            \
    f16x8 Bhf[8], Blf[8];                                                      \
    _Pragma("unroll") for (int c_ = 0; c_ < 8; ++c_) {                         \
      Bhf[c_] = *(const f16x8*)((BhP) + c_ * 1024 + lane * 16);                \
      Blf[c_] = *(const f16x8*)((BlP) + c_ * 1024 + lane * 16);                \
    }                                                                          \
    f16x8 Ah[2], Al[2];                                                        \
    _Pragma("unroll") for (int rt_ = 0; rt_ < 2; ++rt_) {                      \
      const int row_ = w * 32 + rt_ * 16 + l15;                                \
      const int sw_ = (row_ & 7) << 4;                                         \
      const char* rb_ = (AsP) + row_ * 128;                                    \
      const f32x4 a0_ = *(const f32x4*)(rb_ + ((lg * 32) ^ sw_));              \
      const f32x4 a1_ = *(const f32x4*)(rb_ + ((lg * 32 + 16) ^ sw_));         \
      CVT8(rt_, a0_, a1_)                                                      \
    }                                                                          \
    _Pragma("unroll") for (int c_ = 0; c_ < 8; ++c_)                           \
        _Pragma("unroll") for (int rt_ = 0; rt_ < 2; ++rt_)                    \
            acc[rt_][c_] = __builtin_amdgcn_mfma_f32_16x16x32_f16(             \
                Ah[rt_], Bhf[c_], acc[rt_][c_], 0, 0, 0);                      \
    _Pragma("unroll") for (int c_ = 0; c_ < 8; ++c_)                           \
        _Pragma("unroll") for (int rt_ = 0; rt_ < 2; ++rt_)                    \
            acc[rt_][c_] = __builtin_amdgcn_mfma_f32_16x16x32_f16(             \
                Al[rt_], Bhf[c_], acc[rt_][c_], 0, 0, 0);                      \
    _Pragma("unroll") for (int c_ = 0; c_ < 8; ++c_)                           \
        _Pragma("unroll") for (int rt_ = 0; rt_ < 2; ++rt_)                    \
            acc[rt_][c_] = __builtin_amdgcn_mfma_f32_16x16x32_f16(             \
                Ah[rt_], Blf[c_], acc[rt_][c_], 0, 0, 0);                      \
  }

__global__ __launch_bounds__(256, 2)
void gemm_dmap(const float* __restrict__ x, const _Float16* __restrict__ ehi,
               const _Float16* __restrict__ elo, const float* __restrict__ esq,
               float* __restrict__ dmap) {
  __shared__ __align__(16) char smem[66048];
  char* const AsA = smem;              // A slab fp32 [128][32] = 16 KB
  char* const AsB = smem + 16384;
  char* const BhA = smem + 32768;      // B hi frag slab 8 KB
  char* const BhB = smem + 40960;
  char* const BlA = smem + 49152;      // B lo frag slab 8 KB
  char* const BlB = smem + 57344;
  float* const esqt = (float*)(smem + 65536);

  const int t = threadIdx.x;
  const int w = t >> 6;
  const int lane = t & 63;
  const int l15 = lane & 15;
  const int lg = lane >> 4;

  // XCD-aware remap (bijective only when rowblocks%8==0; else identity)
  int mt, nt;
  const int rowblocks = gridDim.x >> 3;
  if ((rowblocks & 7) == 0) {
    const int r = blockIdx.x & 7;        // ~XCD id (dispatch round-robin)
    const int q = blockIdx.x >> 3;
    mt = q & 7;
    nt = r + 8 * (q >> 3);
  } else {
    mt = blockIdx.x & 7;
    nt = blockIdx.x >> 3;
  }
  const int n0 = nt * 128;

  if (t < 128) esqt[t] = esq[mt * 128 + t];

  f32x4 acc[2][8];
#pragma unroll
  for (int rt = 0; rt < 2; ++rt)
#pragma unroll
    for (int c = 0; c < 8; ++c) acc[rt][c] = (f32x4){0.f, 0.f, 0.f, 0.f};

  STAGE(AsA, BhA, BlA, 0)
  __syncthreads();

  for (int kk = 0; kk < 8; ++kk) {
    const int ks = kk * 2;
    STAGE(AsB, BhB, BlB, ks + 1)
    COMPUTE(AsA, BhA, BlA)
    __syncthreads();
    if (ks + 2 < 16) STAGE(AsA, BhA, BlA, ks + 2)
    COMPUTE(AsB, BhB, BlB)
    __syncthreads();
  }

#pragma unroll
  for (int rt = 0; rt < 2; ++rt)
#pragma unroll
    for (int ct = 0; ct < 8; ++ct) {
      const float e5 = 5.f * esqt[ct * 16 + l15];
      float* dr = dmap + (size_t)(n0 + w * 32 + rt * 16 + lg * 4) * 1024 +
                  mt * 128 + ct * 16 + l15;
#pragma unroll
      for (int rg = 0; rg < 4; ++rg)
        dr[(size_t)rg * 1024] = 10.f * acc[rt][ct][rg] - e5;
    }
}

// ---------------------------------------------------------------------------
#define AMAX(V, MM)                                                            \
  { const float v_ = (V); const int m_ = (MM);                                 \
    if (v_ > bv || (v_ == bv && m_ < bi)) { bv = v_; bi = m_; } }
#define GMAXD(V, MM, DV)                                                       \
  { const float v_ = (V); const int m_ = (MM);                                 \
    if (v_ > gv || (v_ == gv && m_ < gi)) { gv = v_; gi = m_; dv = (DV); } }

// per-row work: argmax->counts_rep, softmax->cav, gumbel argmax->(gi,dv),
// gather emb[gi]->out, sd_wave += dmap'[n][gi]  (SSE identity, no x read)
#define ROWBODY(N)                                                             \
  {                                                                            \
    const int n_ = (N);                                                        \
    const float* Dr = dmap + (size_t)n_ * MDIM;                                \
    const float4* grow = (const float4*)(gum + (size_t)n_ * MDIM);             \
    const float4 q0 = grow[lane];                                              \
    const float4 q1 = grow[lane + 64];                                         \
    const float4 q2 = grow[lane + 128];                                        \
    const float4 q3 = grow[lane + 192];                                        \
    const float4 d0 = *(const float4*)&Dr[co];                                 \
    const float4 d1 = *(const float4*)&Dr[co + 256];                           \
    const float4 d2 = *(const float4*)&Dr[co + 512];                           \
    const float4 d3 = *(const float4*)&Dr[co + 768];                           \
    float bv = -3.402823466e+38f; int bi = 0;                                  \
    AMAX(d0.x, co + 0)   AMAX(d0.y, co + 1)   AMAX(d0.z, co + 2)   AMAX(d0.w, co + 3)   \
    AMAX(d1.x, co + 256) AMAX(d1.y, co + 257) AMAX(d1.z, co + 258) AMAX(d1.w, co + 259) \
    AMAX(d2.x, co + 512) AMAX(d2.y, co + 513) AMAX(d2.z, co + 514) AMAX(d2.w, co + 515) \
    AMAX(d3.x, co + 768) AMAX(d3.y, co + 769) AMAX(d3.z, co + 770) AMAX(d3.w, co + 771) \
    _Pragma("unroll") for (int off = 32; off; off >>= 1) {                     \
      const float ov = __shfl_xor(bv, off);                                    \
      const int oi = __shfl_xor(bi, off);                                      \
      if (ov > bv || (ov == bv && oi < bi)) { bv = ov; bi = oi; }              \
    }                                                                          \
    if (lane == 0) atomicAdd(&counts_rep[rep + bi], 1);                        \
    float4 p0, p1, p2, p3;                                                     \
    p0.x = __expf(d0.x - bv); p0.y = __expf(d0.y - bv);                        \
    p0.z = __expf(d0.z - bv); p0.w = __expf(d0.w - bv);                        \
    p1.x = __expf(d1.x - bv); p1.y = __expf(d1.y - bv);                        \
    p1.z = __expf(d1.z - bv); p1.w = __expf(d1.w - bv);                        \
    p2.x = __expf(d2.x - bv); p2.y = __expf(d2.y - bv);                        \
    p2.z = __expf(d2.z - bv); p2.w = __expf(d2.w - bv);                        \
    p3.x = __expf(d3.x - bv); p3.y = __expf(d3.y - bv);                        \
    p3.z = __expf(d3.z - bv); p3.w = __expf(d3.w - bv);                        \
    float ssum = (((p0.x + p0.y) + (p0.z + p0.w)) + ((p1.x + p1.y) + (p1.z + p1.w))) + \
                 (((p2.x + p2.y) + (p2.z + p2.w)) + ((p3.x + p3.y) + (p3.z + p3.w)));  \
    _Pragma("unroll") for (int off = 32; off; off >>= 1)                       \
        ssum += __shfl_xor(ssum, off);                                         \
    const float inv = 1.0f / ssum;                                             \
    cav0.x += p0.x * inv; cav0.y += p0.y * inv;                                \
    cav0.z += p0.z * inv; cav0.w += p0.w * inv;                                \
    cav1.x += p1.x * inv; cav1.y += p1.y * inv;                                \
    cav1.z += p1.z * inv; cav1.w += p1.w * inv;                                \
    cav2.x += p2.x * inv; cav2.y += p2.y * inv;                                \
    cav2.z += p2.z * inv; cav2.w += p2.w * inv;                                \
    cav3.x += p3.x * inv; cav3.y += p3.y * inv;                                \
    cav3.z += p3.z * inv; cav3.w += p3.w * inv;                                \
    float gv = -3.402823466e+38f, dv = 0.f; int gi = 0;                        \
    GMAXD(d0.x + q0.x, co + 0, d0.x)     GMAXD(d0.y + q0.y, co + 1, d0.y)      \
    GMAXD(d0.z + q0.z, co + 2, d0.z)     GMAXD(d0.w + q0.w, co + 3, d0.w)      \
    GMAXD(d1.x + q1.x, co + 256, d1.x)   GMAXD(d1.y + q1.y, co + 257, d1.y)    \
    GMAXD(d1.z + q1.z, co + 258, d1.z)   GMAXD(d1.w + q1.w, co + 259, d1.w)    \
    GMAXD(d2.x + q2.x, co + 512, d2.x)   GMAXD(d2.y + q2.y, co + 513, d2.y)    \
    GMAXD(d2.z + q2.z, co + 514, d2.z)   GMAXD(d2.w + q2.w, co + 515, d2.w)    \
    GMAXD(d3.x + q3.x, co + 768, d3.x)   GMAXD(d3.y + q3.y, co + 769, d3.y)    \
    GMAXD(d3.z + q3.z, co + 770, d3.z)   GMAXD(d3.w + q3.w, co + 771, d3.w)    \
    _Pragma("unroll") for (int off = 32; off; off >>= 1) {                     \
      const float ov = __shfl_xor(gv, off);                                    \
      const int oi = __shfl_xor(gi, off);                                      \
      const float od = __shfl_xor(dv, off);                                    \
      if (ov > gv || (ov == gv && oi < gi)) { gv = ov; gi = oi; dv = od; }     \
    }                                                                          \
    sd_wave += dv;                                                             \
    const float4* erow = (const float4*)(emb + (size_t)gi * DDIM);             \
    float4* orow = (float4*)(out + (size_t)n_ * DDIM);                         \
    orow[lane] = erow[lane];                                                   \
    orow[lane + 64] = erow[lane + 64];                                         \
  }

// Streaming epilogue: r11-verbatim hot path (proven optimum over 7 variants)
// + r16 heterogeneous-grid xsq: blocks >= nepi stream sum(x^2) into the idle
// CU capacity of this latency-bound kernel (replaces the serial xsq kernel).
__global__ __launch_bounds__(256)
void epi(const float* __restrict__ xfull, const float* __restrict__ emb,
         const float* __restrict__ dmap, const float* __restrict__ gum,
         float* __restrict__ out, float* __restrict__ avg_rep,
         int* __restrict__ counts_rep, float* __restrict__ sd_rep,
         float* __restrict__ xsq_rep, int nepi) {
  __shared__ float avg_s[MDIM];
  const int t = threadIdx.x;
  const int lane = t & 63;

  if ((int)blockIdx.x >= nepi) {
    // ---- xsq tail blocks: 64 blocks x 256 thr, strided over all of x ----
    const int xb = blockIdx.x - nepi;          // 0..63
    const int tid = xb * 256 + t;              // 0..16383
    const float4* xv = (const float4*)xfull;
    float s = 0.f;
#pragma unroll 8
    for (int i = 0; i < 256; ++i) {            // 4,194,304 float4 total
      const float4 a = xv[(size_t)i * 16384 + tid];
      s += (a.x * a.x + a.y * a.y) + (a.z * a.z + a.w * a.w);
    }
#pragma unroll
    for (int off = 32; off; off >>= 1) s += __shfl_xor(s, off);
    if (lane == 0) atomicAdd(&xsq_rep[(xb & (NREP - 1)) * 16], s);
    return;
  }

  const int w = t >> 6;
  const int co = lane << 2;
  const int rep = (blockIdx.x & (NREP - 1)) * MDIM;  // this block's replica
  avg_s[t] = 0.f; avg_s[t + 256] = 0.f; avg_s[t + 512] = 0.f; avg_s[t + 768] = 0.f;
  __syncthreads();

  float4 cav0 = make_float4(0.f, 0.f, 0.f, 0.f);
  float4 cav1 = make_float4(0.f, 0.f, 0.f, 0.f);
  float4 cav2 = make_float4(0.f, 0.f, 0.f, 0.f);
  float4 cav3 = make_float4(0.f, 0.f, 0.f, 0.f);
  float sd_wave = 0.f;

  const int nb = blockIdx.x * 32 + w * 8;  // chunk-local row base (8 rows)
  for (int i = 0; i < 8; ++i) {
    ROWBODY(nb + i)
  }

  if (lane == 0) atomicAdd(&sd_rep[(blockIdx.x & (NREP - 1)) * 16], sd_wave);

  atomicAdd(&avg_s[co + 0], cav0.x);   atomicAdd(&avg_s[co + 1], cav0.y);
  atomicAdd(&avg_s[co + 2], cav0.z);   atomicAdd(&avg_s[co + 3], cav0.w);
  atomicAdd(&avg_s[co + 256], cav1.x); atomicAdd(&avg_s[co + 257], cav1.y);
  atomicAdd(&avg_s[co + 258], cav1.z); atomicAdd(&avg_s[co + 259], cav1.w);
  atomicAdd(&avg_s[co + 512], cav2.x); atomicAdd(&avg_s[co + 513], cav2.y);
  atomicAdd(&avg_s[co + 514], cav2.z); atomicAdd(&avg_s[co + 515], cav2.w);
  atomicAdd(&avg_s[co + 768], cav3.x); atomicAdd(&avg_s[co + 769], cav3.y);
  atomicAdd(&avg_s[co + 770], cav3.z); atomicAdd(&avg_s[co + 771], cav3.w);
  __syncthreads();
  atomicAdd(&avg_rep[rep + t], avg_s[t]);
  atomicAdd(&avg_rep[rep + t + 256], avg_s[t + 256]);
  atomicAdd(&avg_rep[rep + t + 512], avg_s[t + 512]);
  atomicAdd(&avg_rep[rep + t + 768], avg_s[t + 768]);
}

// ---------------------------------------------------------------------------
__global__ __launch_bounds__(1024)
void finalize(const float* __restrict__ avg_rep, const int* __restrict__ counts_rep,
              const float* __restrict__ sd_rep, const float* __restrict__ xsq_rep,
              float* __restrict__ out) {
  __shared__ float red[32];
  const int t = threadIdx.x;
  float q = 0.f; int c = 0;
#pragma unroll
  for (int r = 0; r < NREP; ++r) {
    q += avg_rep[r * MDIM + t];
    c += counts_rep[r * MDIM + t];
  }
  const float invN = 1.f / 32768.f;
  const float p = (float)c * invN;
  float a = p * log2f(p + 1e-10f);
  const float qq = q * invN;
  float b = qq * log2f(qq + 1e-10f);
#pragma unroll
  for (int off = 32; off; off >>= 1) {
    a += __shfl_xor(a, off);
    b += __shfl_xor(b, off);
  }
  const int wv = t >> 6, ln = t & 63;
  if (ln == 0) { red[wv] = a; red[wv + 16] = b; }
  __syncthreads();
  if (t == 0) {
    float sa = 0.f, sb = 0.f;
#pragma unroll
    for (int i = 0; i < 16; ++i) { sa += red[i]; sb += red[i + 16]; }
    float sd = 0.f, xs = 0.f;
#pragma unroll
    for (int r = 0; r < NREP; ++r) { sd += sd_rep[r * 16]; xs += xsq_rep[r * 16]; }
    out[QOFF + 0] = -sa;                                // code_perplexity
    out[QOFF + 1] = -sb;                                // prob_perplexity
    const float sse = xs - sd * 0.2f;                   // SSE identity
    out[QOFF + 2] = sse * (1.f / (32768.f * 512.f));    // commitment_loss
  }
}

// ---------------------------------------------------------------------------
extern "C" void kernel_launch(void* const* d_in, const int* in_sizes, int n_in,
                              void* d_out, int out_size, void* d_ws,
                              size_t ws_size, hipStream_t stream) {
  const float* x = (const float*)d_in[0];
  const float* e = (const float*)d_in[1];
  const float* g = (const float*)d_in[2];
  float* out = (float*)d_out;
  char* wsb = (char*)d_ws;
  // ws layout (bytes):
  //   esq@0 (4K) | avg_rep@16384 (128K) | counts_rep@147456 (128K) |
  //   sd_rep@278528 (2K) | xsq_rep@280576 (2K) | ehi@282624 (1M) |
  //   elo@+1M | dmap@2379776
  float* esq = (float*)wsb;
  float* avg_rep = (float*)(wsb + 16384);
  int* counts_rep = (int*)(wsb + 147456);
  float* sd_rep = (float*)(wsb + 278528);
  float* xsq_rep = (float*)(wsb + 280576);
  _Float16* ehi = (_Float16*)(wsb + 282624);
  _Float16* elo = (_Float16*)(wsb + 282624 + 1048576);
  float* dmap = (float*)(wsb + 2379776);

  // chunk rows so dmap (4 KB/row fp32) fits in the remaining workspace
  const size_t cap = (ws_size > 2379776) ? ws_size - 2379776 : 0;
  long long cr = (long long)(cap / 4096);
  cr = (cr / 128) * 128;
  if (cr > NTOT) cr = NTOT;
  if (cr < 128) cr = 128;
  const int chunk_rows = (int)cr;

  // zero esq + all replicated accumulators (avg, counts, sd, xsq)
  hipMemsetAsync(wsb, 0, 282624, stream);

  e_to_frag<<<256, 256, 0, stream>>>(e, ehi, elo, esq);

  for (int n0 = 0; n0 < NTOT; n0 += chunk_rows) {
    const int rows = (NTOT - n0 < chunk_rows) ? (NTOT - n0) : chunk_rows;
    const int nepi = rows / 32;
    const int extra = (n0 == 0) ? 64 : 0;  // xsq tail blocks, once
    gemm_dmap<<<8 * (rows / 128), 256, 0, stream>>>(
        x + (size_t)n0 * DDIM, ehi, elo, esq, dmap);
    epi<<<nepi + extra, 256, 0, stream>>>(
        x, e, dmap, g + (size_t)n0 * MDIM, out + (size_t)n0 * DDIM,
        avg_rep, counts_rep, sd_rep, xsq_rep, nepi);
  }
  finalize<<<1, 1024, 0, stream>>>(avg_rep, counts_rep, sd_rep, xsq_rep, out);
}